// Round 3
// baseline (126.227 us; speedup 1.0000x reference)
//
#include <hip/hip_runtime.h>

typedef float f32x4 __attribute__((ext_vector_type(4)));

// ---------------------------------------------------------------------------
// Fused kernel: every block (a) computes the exact k-th-largest threshold of
// kernel[0..D) via a bitwise binary search on order-preserving uint transforms
// (~5 iterations since the values span ~16 ULPs; cost ~2 us, fully parallel
// across the co-resident grid), then (b) streams out[i] = x[i] * sel, with the
// per-thread sel value hoisted out of the loop (valid because
// stride % (D/4) == 0, so each thread's column is fixed).
// ---------------------------------------------------------------------------
__global__ void __launch_bounds__(256)
fused_select_mul(const f32x4* __restrict__ x,
                 const float* __restrict__ kern,
                 const int* __restrict__ kptr,
                 f32x4* __restrict__ out,
                 int D, int n4)
{
    const int tid  = threadIdx.x;
    const int lane = tid & 63;
    const int wid  = tid >> 6;

    __shared__ unsigned int s_umin[4], s_umax[4];
    __shared__ int s_cnt[4];

    // ---- Phase 1: exact k-th-largest threshold (per block, redundant) ----
    // order-preserving transform: u = b ^ ((int(b)>>31) | 0x80000000)
    unsigned int u[16];
    #pragma unroll
    for (int j = 0; j < 16; ++j) {
        int i = tid + j * 256;
        if (i < D) {
            unsigned int b = __float_as_uint(kern[i]);
            u[j] = b ^ (unsigned int)(((int)b >> 31) | (int)0x80000000);
        } else {
            u[j] = 0u;  // pads sort below all real values
        }
    }

    unsigned int umin = 0xFFFFFFFFu, umax = 0u;
    #pragma unroll
    for (int j = 0; j < 16; ++j) {
        int i = tid + j * 256;
        if (i < D) { umin = min(umin, u[j]); umax = max(umax, u[j]); }
    }
    #pragma unroll
    for (int off = 32; off; off >>= 1) {
        umin = min(umin, (unsigned int)__shfl_down((int)umin, off, 64));
        umax = max(umax, (unsigned int)__shfl_down((int)umax, off, 64));
    }
    if (lane == 0) { s_umin[wid] = umin; s_umax[wid] = umax; }
    __syncthreads();
    umin = min(min(s_umin[0], s_umin[1]), min(s_umin[2], s_umin[3]));
    umax = max(max(s_umax[0], s_umax[1]), max(s_umax[2], s_umax[3]));

    const int kk = *kptr;
    unsigned int t;
    unsigned int xorv = umin ^ umax;
    if (xorv == 0u) {
        t = umax;
    } else {
        int hb = 31 - __builtin_clz(xorv);
        unsigned int lowmask = (hb == 31) ? 0xFFFFFFFFu : ((1u << (hb + 1)) - 1u);
        t = umax & ~lowmask;  // common prefix
        for (int bit = hb; bit >= 0; --bit) {
            unsigned int cand = t | (1u << bit);
            int c = 0;
            #pragma unroll
            for (int j = 0; j < 16; ++j) c += (u[j] >= cand) ? 1 : 0;
            #pragma unroll
            for (int off = 32; off; off >>= 1) c += __shfl_down(c, off, 64);
            __syncthreads();                 // protect s_cnt reuse
            if (lane == 0) s_cnt[wid] = c;
            __syncthreads();
            c = s_cnt[0] + s_cnt[1] + s_cnt[2] + s_cnt[3];
            if (c >= kk) t = cand;
        }
    }
    const float thr = __uint_as_float((t & 0x80000000u) ? (t ^ 0x80000000u) : ~t);

    // ---- Phase 2: streaming broadcast multiply ----
    const int gid    = blockIdx.x * 256 + tid;
    const int stride = gridDim.x * 256;
    const int d4mask = (D >> 2) - 1;
    const f32x4* kern4 = (const f32x4*)kern;

    if ((stride & d4mask) == 0) {
        // each thread's column is fixed -> hoist sel out of the loop
        f32x4 kv = kern4[gid & d4mask];
        f32x4 sv;
        sv.x = (kv.x < thr) ? 0.0f : kv.x;
        sv.y = (kv.y < thr) ? 0.0f : kv.y;
        sv.z = (kv.z < thr) ? 0.0f : kv.z;
        sv.w = (kv.w < thr) ? 0.0f : kv.w;

        int i = gid;
        for (; i + 3 * stride < n4; i += 4 * stride) {
            f32x4 a0 = __builtin_nontemporal_load(&x[i]);
            f32x4 a1 = __builtin_nontemporal_load(&x[i + stride]);
            f32x4 a2 = __builtin_nontemporal_load(&x[i + 2 * stride]);
            f32x4 a3 = __builtin_nontemporal_load(&x[i + 3 * stride]);
            __builtin_nontemporal_store(a0 * sv, &out[i]);
            __builtin_nontemporal_store(a1 * sv, &out[i + stride]);
            __builtin_nontemporal_store(a2 * sv, &out[i + 2 * stride]);
            __builtin_nontemporal_store(a3 * sv, &out[i + 3 * stride]);
        }
        for (; i < n4; i += stride) {
            f32x4 a = __builtin_nontemporal_load(&x[i]);
            __builtin_nontemporal_store(a * sv, &out[i]);
        }
    } else {
        // generic fallback: per-iteration sel
        for (int i = gid; i < n4; i += stride) {
            f32x4 kv = kern4[i & d4mask];
            f32x4 sv;
            sv.x = (kv.x < thr) ? 0.0f : kv.x;
            sv.y = (kv.y < thr) ? 0.0f : kv.y;
            sv.z = (kv.z < thr) ? 0.0f : kv.z;
            sv.w = (kv.w < thr) ? 0.0f : kv.w;
            f32x4 a = __builtin_nontemporal_load(&x[i]);
            __builtin_nontemporal_store(a * sv, &out[i]);
        }
    }
}

extern "C" void kernel_launch(void* const* d_in, const int* in_sizes, int n_in,
                              void* d_out, int out_size, void* d_ws, size_t ws_size,
                              hipStream_t stream) {
    const float* x    = (const float*)d_in[0];
    const float* kern = (const float*)d_in[1];
    const int*   kptr = (const int*)d_in[2];
    float* out = (float*)d_out;

    const int D  = in_sizes[1];
    const int n4 = out_size / 4;   // B*D / 4, D=4096 -> divisible

    // 2048 blocks x 256 threads = exactly 8 blocks/CU co-resident;
    // stride (524288) is a multiple of D/4 (1024) -> hoisted-sel fast path.
    const int blocks = 2048;
    fused_select_mul<<<blocks, 256, 0, stream>>>(
        (const f32x4*)x, kern, kptr, (f32x4*)out, D, n4);
}

// Round 4
// 113.729 us; speedup vs baseline: 1.1099x; 1.1099x over previous
//
#include <hip/hip_runtime.h>

typedef float f32x4 __attribute__((ext_vector_type(4)));

// ---------------------------------------------------------------------------
// Kernel A: exact k-th-largest threshold via bitwise binary search on
// order-preserving uint transforms, then emit sel[d] = (kern[d]<thr)?0:kern[d].
// Single block, 256 threads, values in registers (16/thread for D=4096).
// Values span ~16 ULPs -> search runs ~5 iterations. ~3 us.
// ---------------------------------------------------------------------------
__global__ void __launch_bounds__(256)
select_threshold_kernel(const float* __restrict__ kern,
                        const int* __restrict__ kptr,
                        float* __restrict__ sel,
                        int D) {
    const int tid  = threadIdx.x;
    const int lane = tid & 63;
    const int wid  = tid >> 6;

    __shared__ unsigned int s_umin[4], s_umax[4];
    __shared__ int s_cnt[4];

    unsigned int u[16];
    #pragma unroll
    for (int j = 0; j < 16; ++j) {
        int i = tid + j * 256;
        if (i < D) {
            unsigned int b = __float_as_uint(kern[i]);
            u[j] = b ^ (unsigned int)(((int)b >> 31) | (int)0x80000000);
        } else {
            u[j] = 0u;
        }
    }

    unsigned int umin = 0xFFFFFFFFu, umax = 0u;
    #pragma unroll
    for (int j = 0; j < 16; ++j) {
        int i = tid + j * 256;
        if (i < D) { umin = min(umin, u[j]); umax = max(umax, u[j]); }
    }
    #pragma unroll
    for (int off = 32; off; off >>= 1) {
        umin = min(umin, (unsigned int)__shfl_down((int)umin, off, 64));
        umax = max(umax, (unsigned int)__shfl_down((int)umax, off, 64));
    }
    if (lane == 0) { s_umin[wid] = umin; s_umax[wid] = umax; }
    __syncthreads();
    umin = min(min(s_umin[0], s_umin[1]), min(s_umin[2], s_umin[3]));
    umax = max(max(s_umax[0], s_umax[1]), max(s_umax[2], s_umax[3]));

    const int kk = *kptr;
    unsigned int t;
    unsigned int xorv = umin ^ umax;
    if (xorv == 0u) {
        t = umax;
    } else {
        int hb = 31 - __builtin_clz(xorv);
        unsigned int lowmask = (hb == 31) ? 0xFFFFFFFFu : ((1u << (hb + 1)) - 1u);
        t = umax & ~lowmask;
        for (int bit = hb; bit >= 0; --bit) {
            unsigned int cand = t | (1u << bit);
            int c = 0;
            #pragma unroll
            for (int j = 0; j < 16; ++j) c += (u[j] >= cand) ? 1 : 0;
            #pragma unroll
            for (int off = 32; off; off >>= 1) c += __shfl_down(c, off, 64);
            __syncthreads();
            if (lane == 0) s_cnt[wid] = c;
            __syncthreads();
            c = s_cnt[0] + s_cnt[1] + s_cnt[2] + s_cnt[3];
            if (c >= kk) t = cand;
        }
    }

    float thr = __uint_as_float((t & 0x80000000u) ? (t ^ 0x80000000u) : ~t);

    #pragma unroll
    for (int j = 0; j < 16; ++j) {
        int i = tid + j * 256;
        if (i < D) {
            float v = kern[i];
            sel[i] = (v < thr) ? 0.0f : v;
        }
    }
}

// ---------------------------------------------------------------------------
// Kernel B: out[i] = x[i] * sel, simple 1-load/1-store NT stream (the round-1
// pattern that measured best), with the loop-invariant sel value hoisted:
// stride % (D/4) == 0 so each thread's column is fixed for all iterations.
// ---------------------------------------------------------------------------
__global__ void __launch_bounds__(256)
bcast_mul_kernel(const f32x4* __restrict__ x,
                 const f32x4* __restrict__ sel,
                 f32x4* __restrict__ out,
                 int n4, int d4mask) {
    const int gid    = blockIdx.x * 256 + threadIdx.x;
    const int stride = gridDim.x * 256;

    if ((stride & d4mask) == 0) {
        const f32x4 sv = sel[gid & d4mask];   // hoisted: column fixed per thread
        for (int i = gid; i < n4; i += stride) {
            f32x4 xv = __builtin_nontemporal_load(&x[i]);
            __builtin_nontemporal_store(xv * sv, &out[i]);
        }
    } else {
        for (int i = gid; i < n4; i += stride) {
            f32x4 xv = __builtin_nontemporal_load(&x[i]);
            f32x4 sv = sel[i & d4mask];
            __builtin_nontemporal_store(xv * sv, &out[i]);
        }
    }
}

extern "C" void kernel_launch(void* const* d_in, const int* in_sizes, int n_in,
                              void* d_out, int out_size, void* d_ws, size_t ws_size,
                              hipStream_t stream) {
    const float* x    = (const float*)d_in[0];
    const float* kern = (const float*)d_in[1];
    const int*   kptr = (const int*)d_in[2];
    float* out = (float*)d_out;
    float* sel = (float*)d_ws;  // D floats = 16 KiB scratch

    const int D = in_sizes[1];

    // Phase 1: exact threshold + selected kernel vector (single block)
    select_threshold_kernel<<<1, 256, 0, stream>>>(kern, kptr, sel, D);

    // Phase 2: streaming broadcast multiply.
    // 2048 blocks x 256 threads: 8 blocks/CU; stride 524288 is a multiple of
    // D/4=1024 -> hoisted-sel fast path.
    const int n4 = out_size / 4;
    const int d4mask = (D / 4) - 1;
    bcast_mul_kernel<<<2048, 256, 0, stream>>>(
        (const f32x4*)x, (const f32x4*)sel, (f32x4*)out, n4, d4mask);
}